// Round 14
// baseline (467.310 us; speedup 1.0000x reference)
//
#include <hip/hip_runtime.h>

#define NN 100000
#define EE 1600000
#define NBKT 391      // ceil(NN/256): buckets of 256 dst nodes
#define NCHK 391      // ceil(EE/4096): edge chunks for count/bin
#define BINCHUNK 4096
#define CAP 5120      // LDS record capacity in k_sort (mean 4092, +16 sigma)

typedef unsigned int uint;
typedef unsigned short ushort;
typedef unsigned long long u64;

__device__ inline ushort f2bf(float f) {          // RNE float->bf16
    uint u = __float_as_uint(f);
    return (ushort)((u + 0x7fffu + ((u >> 16) & 1u)) >> 16);
}
__device__ inline float bf_lo(uint u) { return __uint_as_float(u << 16); }
__device__ inline float bf_hi(uint u) { return __uint_as_float(u & 0xffff0000u); }
__device__ inline float bf2f(ushort s) { return __uint_as_float((uint)s << 16); }

// ---------- pass 1: per-bucket edge counts ----------
__global__ __launch_bounds__(256) void k_count(const int* __restrict__ dst,
                                               int* __restrict__ gcount) {
    __shared__ int bh[NBKT];
    int t = threadIdx.x;
    for (int i = t; i < NBKT; i += 256) bh[i] = 0;
    __syncthreads();
    int base = blockIdx.x * BINCHUNK;
    int lim = min(EE - base, BINCHUNK);
    for (int i = t; i < lim; i += 256) atomicAdd(&bh[dst[base + i] >> 8], 1);
    __syncthreads();
    for (int i = t; i < NBKT; i += 256)
        if (bh[i]) atomicAdd(&gcount[i], bh[i]);
}

// ---------- scan bucket counts -> bucket offsets (+cursor init) ----------
__global__ __launch_bounds__(512) void k_bscan(const int* __restrict__ gcount,
                                               int* __restrict__ bofs,
                                               int* __restrict__ gcursor,
                                               int* __restrict__ rowptr) {
    __shared__ int buf[2][512];
    int t = threadIdx.x;
    int v = (t < NBKT) ? gcount[t] : 0;
    int pi = 0;
    buf[0][t] = v;
    __syncthreads();
    for (int off = 1; off < 512; off <<= 1) {
        int po = pi ^ 1;
        int add = (t >= off) ? buf[pi][t - off] : 0;
        buf[po][t] = buf[pi][t] + add;
        __syncthreads();
        pi = po;
    }
    int excl = buf[pi][t] - v;
    if (t < NBKT) { bofs[t] = excl; gcursor[t] = excl; }
    if (t == 0) { bofs[NBKT] = EE; rowptr[NN] = EE; }
}

// ---------- pass 2: bin edges into bucket-major record array ----------
// record u64: [ew_f32 : bits 25..56][src : bits 8..24][dst&255 : bits 0..7]
__global__ __launch_bounds__(256) void k_bin(const int* __restrict__ src,
                                             const int* __restrict__ dst,
                                             const float* __restrict__ ew,
                                             int* __restrict__ gcursor,
                                             u64* __restrict__ recs) {
    __shared__ int bh[NBKT], start[NBKT], lc[NBKT];
    int t = threadIdx.x;
    for (int i = t; i < NBKT; i += 256) { bh[i] = 0; lc[i] = 0; }
    __syncthreads();
    int base = blockIdx.x * BINCHUNK;
    int lim = min(EE - base, BINCHUNK);
    for (int i = t; i < lim; i += 256) atomicAdd(&bh[dst[base + i] >> 8], 1);
    __syncthreads();
    for (int i = t; i < NBKT; i += 256)
        if (bh[i]) start[i] = atomicAdd(&gcursor[i], bh[i]);
    __syncthreads();
    for (int i = t; i < lim; i += 256) {
        int e = base + i;
        int d = dst[e];
        int b = d >> 8;
        int r = atomicAdd(&lc[b], 1);
        recs[start[b] + r] = ((u64)__float_as_uint(ew[e]) << 25) |
                             ((u64)(uint)src[e] << 8) | (u64)(uint)(d & 255);
    }
}

// ---------- pass 3: per-bucket sort by dst + deg/dis/rowptr (in-place epk) ----------
__global__ __launch_bounds__(256) void k_sort(const u64* __restrict__ recs,
                                              const int* __restrict__ bofs,
                                              float* __restrict__ dis,
                                              int* __restrict__ rowptr,
                                              int2* __restrict__ epk) {
    __shared__ u64 rl[CAP];
    __shared__ int hist[256], cur[256];
    __shared__ float degf[256];
    __shared__ int sb[2][256];
    int t = threadIdx.x;
    int b = blockIdx.x;
    int base = bofs[b], cnt = bofs[b + 1] - base;
    hist[t] = 0; cur[t] = 0; degf[t] = 0.f;
    __syncthreads();
    for (int i = t; i < cnt; i += 256) {
        u64 r = recs[base + i];
        if (i < CAP) rl[i] = r;
        int dl = (int)(r & 255);
        atomicAdd(&hist[dl], 1);
        atomicAdd(&degf[dl], __uint_as_float((uint)(r >> 25)));
    }
    __syncthreads();
    // exclusive scan of hist -> per-node local offsets
    int v = hist[t];
    int pi = 0;
    sb[0][t] = v;
    __syncthreads();
    for (int off = 1; off < 256; off <<= 1) {
        int po = pi ^ 1;
        int add = (t >= off) ? sb[pi][t - off] : 0;
        sb[po][t] = sb[pi][t] + add;
        __syncthreads();
        pi = po;
    }
    int lofs = sb[pi][t] - v;
    int node = (b << 8) + t;
    if (node < NN) {
        dis[node] = rsqrtf(1.0f + degf[t]);      // self-loop weight 1
        rowptr[node] = base + lofs;
    }
    hist[t] = lofs;                               // reuse as offset table
    __syncthreads();
    for (int i = t; i < cnt; i += 256) {
        u64 r = (i < CAP) ? rl[i] : recs[base + i];
        int dl = (int)(r & 255);
        int pos = hist[dl] + atomicAdd(&cur[dl], 1);
        epk[base + pos] = make_int2((int)((r >> 8) & 0x1FFFF), (int)(uint)(r >> 25));
    }
}

// ---------- pass 4: fold dis[src] into stored weight (L2-friendly) ----------
__global__ __launch_bounds__(256) void k_wmul(int2* __restrict__ epk,
                                              const float* __restrict__ dis) {
    int e = blockIdx.x * blockDim.x + threadIdx.x;
    if (e >= EE) return;
    int2 p = epk[e];
    float w = dis[p.x] * __int_as_float(p.y);
    epk[e] = make_int2(p.x, __float_as_int(w));
}

// ---------- GEMM1: h1[N,128](bf16) = x[N,128] @ W1[128,128] ----------
__global__ __launch_bounds__(256) void k_gemm1(const float* __restrict__ x,
                                               const float* __restrict__ W,
                                               ushort* __restrict__ h) {
    __shared__ float Wl[128 * 128];   // 64 KB
    __shared__ float xt[128 * 32];    // transposed [k][r]
    int t = threadIdx.x;
    int rb = blockIdx.x * 32;

    const float4* W4 = (const float4*)W;
    float4* Wl4 = (float4*)Wl;
#pragma unroll
    for (int i = 0; i < 16; i++) Wl4[t + 256 * i] = W4[t + 256 * i];

#pragma unroll
    for (int i = 0; i < 4; i++) {
        int idx = t + 256 * i;
        int r = idx >> 5;
        int c4 = idx & 31;
        float4 v = ((const float4*)(x + (size_t)(rb + r) * 128))[c4];
        int kc = c4 << 2;
        xt[(kc + 0) * 32 + r] = v.x;
        xt[(kc + 1) * 32 + r] = v.y;
        xt[(kc + 2) * 32 + r] = v.z;
        xt[(kc + 3) * 32 + r] = v.w;
    }
    __syncthreads();

    int tc = t & 31;
    int tr = t >> 5;
    float acc[4][4] = {};
#pragma unroll 4
    for (int k = 0; k < 128; k++) {
        float4 wv = ((const float4*)(Wl + k * 128))[tc];
        float4 xv = ((const float4*)(xt + k * 32))[tr];
        float xs[4] = {xv.x, xv.y, xv.z, xv.w};
        float ws[4] = {wv.x, wv.y, wv.z, wv.w};
#pragma unroll
        for (int r = 0; r < 4; r++)
#pragma unroll
            for (int c = 0; c < 4; c++) acc[r][c] += xs[r] * ws[c];
    }
#pragma unroll
    for (int r = 0; r < 4; r++) {
        int row = rb + tr * 4 + r;
        ushort4 o = {f2bf(acc[r][0]), f2bf(acc[r][1]), f2bf(acc[r][2]), f2bf(acc[r][3])};
        ((ushort4*)(h + (size_t)row * 128))[tc] = o;
    }
}

// ---------- GEMM2: h2[N,64](bf16) = a1[N,128](bf16) @ W2[128,64] ----------
__global__ __launch_bounds__(256) void k_gemm2(const ushort* __restrict__ a,
                                               const float* __restrict__ W,
                                               ushort* __restrict__ h) {
    __shared__ float Wl[128 * 64];     // 32 KB
    __shared__ ushort at[128 * 64];    // 16 KB, transposed [k][r], bf16
    int t = threadIdx.x;
    int rb = blockIdx.x * 64;

    const float4* W4 = (const float4*)W;
    float4* Wl4 = (float4*)Wl;
#pragma unroll
    for (int i = 0; i < 8; i++) Wl4[t + 256 * i] = W4[t + 256 * i];

#pragma unroll
    for (int i = 0; i < 4; i++) {
        int idx = t + 256 * i;          // 0..1023
        int r = idx >> 4;               // 0..63
        int c8 = idx & 15;              // 16 chunks of 8 bf16
        int row = rb + r;
        if (row >= NN) row = NN - 1;    // clamp (garbage rows never stored)
        uint4 u = ((const uint4*)(a + (size_t)row * 128))[c8];
        int kc = c8 << 3;
        at[(kc + 0) * 64 + r] = (ushort)(u.x & 0xffffu);
        at[(kc + 1) * 64 + r] = (ushort)(u.x >> 16);
        at[(kc + 2) * 64 + r] = (ushort)(u.y & 0xffffu);
        at[(kc + 3) * 64 + r] = (ushort)(u.y >> 16);
        at[(kc + 4) * 64 + r] = (ushort)(u.z & 0xffffu);
        at[(kc + 5) * 64 + r] = (ushort)(u.z >> 16);
        at[(kc + 6) * 64 + r] = (ushort)(u.w & 0xffffu);
        at[(kc + 7) * 64 + r] = (ushort)(u.w >> 16);
    }
    __syncthreads();

    int tc = t & 15;
    int tr = t >> 4;
    float acc[4][4] = {};
#pragma unroll 4
    for (int k = 0; k < 128; k++) {
        float4 wv = ((const float4*)(Wl + k * 64))[tc];
        ushort4 av = *(const ushort4*)(at + k * 64 + tr * 4);
        float as[4] = {bf2f(av.x), bf2f(av.y), bf2f(av.z), bf2f(av.w)};
        float ws[4] = {wv.x, wv.y, wv.z, wv.w};
#pragma unroll
        for (int r = 0; r < 4; r++)
#pragma unroll
            for (int c = 0; c < 4; c++) acc[r][c] += as[r] * ws[c];
    }
#pragma unroll
    for (int r = 0; r < 4; r++) {
        int row = rb + tr * 4 + r;
        if (row < NN) {
            ushort4 o = {f2bf(acc[r][0]), f2bf(acc[r][1]), f2bf(acc[r][2]), f2bf(acc[r][3])};
            ((ushort4*)(h + (size_t)row * 64))[tc] = o;
        }
    }
}

// ---------- layer-1 CSR aggregation: one wave per node, 16-way predicated ----------
// a1[d](bf16) = relu( dis[d]*sum_e w[e]*h1[src[e]] + dis[d]^2*h1[d] + b1 )
__global__ __launch_bounds__(256) void k_agg1(const int* __restrict__ rowptr,
                                              const int2* __restrict__ epk,
                                              const float* __restrict__ dis,
                                              const ushort* __restrict__ h,
                                              const float* __restrict__ b,
                                              ushort* __restrict__ a) {
    int wid = (blockIdx.x * blockDim.x + threadIdx.x) >> 6;   // node id
    int lane = threadIdx.x & 63;
    if (wid >= NN) return;
    int beg = rowptr[wid], end = rowptr[wid + 1];
    const uint* hp = (const uint*)h;             // 64 uints (=128 bf16) per row
    uint us = hp[(size_t)wid * 64 + lane];
    float di = dis[wid];
    float2 bv = ((const float2*)b)[lane];

    float2 acc0 = {0.f, 0.f}, acc1 = {0.f, 0.f};
    float2 acc2 = {0.f, 0.f}, acc3 = {0.f, 0.f};
    for (int j = beg; j < end; j += 16) {
        int ps[16]; float ww[16]; uint uu[16];
#pragma unroll
        for (int k = 0; k < 16; k++) {
            int idx = j + k;
            bool vld = idx < end;
            int2 p = epk[vld ? idx : end - 1];
            ps[k] = p.x;
            ww[k] = vld ? __int_as_float(p.y) : 0.f;
        }
#pragma unroll
        for (int k = 0; k < 16; k++) uu[k] = hp[(size_t)ps[k] * 64 + lane];
#pragma unroll
        for (int k = 0; k < 16; k++) {
            float2* A = (k & 3) == 0 ? &acc0 : (k & 3) == 1 ? &acc1
                       : (k & 3) == 2 ? &acc2 : &acc3;
            A->x += ww[k] * bf_lo(uu[k]);
            A->y += ww[k] * bf_hi(uu[k]);
        }
    }
    float sx = (acc0.x + acc1.x) + (acc2.x + acc3.x);
    float sy = (acc0.y + acc1.y) + (acc2.y + acc3.y);
    float ox = di * sx + di * di * bf_lo(us) + bv.x;
    float oy = di * sy + di * di * bf_hi(us) + bv.y;
    ushort2 o = {f2bf(fmaxf(ox, 0.f)), f2bf(fmaxf(oy, 0.f))};
    ((ushort2*)a)[(size_t)wid * 64 + lane] = o;
}

// ---------- layer-2 CSR aggregation: one wave per node, 16-way predicated ----------
__global__ __launch_bounds__(256) void k_agg2(const int* __restrict__ rowptr,
                                              const int2* __restrict__ epk,
                                              const float* __restrict__ dis,
                                              const ushort* __restrict__ h,
                                              const float* __restrict__ b,
                                              float* __restrict__ out) {
    int wid = (blockIdx.x * blockDim.x + threadIdx.x) >> 6;
    int lane = threadIdx.x & 63;
    if (wid >= NN) return;
    int beg = rowptr[wid], end = rowptr[wid + 1];
    float hv = bf2f(h[(size_t)wid * 64 + lane]);
    float di = dis[wid];
    float bl = b[lane];

    float acc0 = 0.f, acc1 = 0.f, acc2 = 0.f, acc3 = 0.f;
    for (int j = beg; j < end; j += 16) {
        int ps[16]; float ww[16]; ushort vv[16];
#pragma unroll
        for (int k = 0; k < 16; k++) {
            int idx = j + k;
            bool vld = idx < end;
            int2 p = epk[vld ? idx : end - 1];
            ps[k] = p.x;
            ww[k] = vld ? __int_as_float(p.y) : 0.f;
        }
#pragma unroll
        for (int k = 0; k < 16; k++) vv[k] = h[(size_t)ps[k] * 64 + lane];
#pragma unroll
        for (int k = 0; k < 16; k++) {
            float val = ww[k] * bf2f(vv[k]);
            if ((k & 3) == 0) acc0 += val;
            else if ((k & 3) == 1) acc1 += val;
            else if ((k & 3) == 2) acc2 += val;
            else acc3 += val;
        }
    }
    float s = (acc0 + acc1) + (acc2 + acc3);
    out[(size_t)wid * 64 + lane] = di * s + di * di * hv + bl;
}

extern "C" void kernel_launch(void* const* d_in, const int* in_sizes, int n_in,
                              void* d_out, int out_size, void* d_ws, size_t ws_size,
                              hipStream_t stream) {
    const float* x  = (const float*)d_in[0];
    const int* ei   = (const int*)d_in[1];
    const float* ew = (const float*)d_in[2];
    const float* W1 = (const float*)d_in[3];
    const float* b1 = (const float*)d_in[4];
    const float* W2 = (const float*)d_in[5];
    const float* b2 = (const float*)d_in[6];
    float* out      = (float*)d_out;

    const int* src = ei;        // edge_index[0]
    const int* dst = ei + EE;   // edge_index[1]

    // workspace layout (4B words):
    int* gcount  = (int*)d_ws;             // 512
    int* bofs    = gcount + 512;           // 512 (NBKT+1 used)
    int* gcursor = bofs + 512;             // 512
    float* dis   = (float*)(gcursor + 512);// 100000
    int* rowptr  = (int*)(dis + 100000);   // 100002 (NN+1 used, pad even)
    u64* recs    = (u64*)(rowptr + 100002);// EE u64 (8B aligned)
    int2* epk    = (int2*)recs;            // ALIAS: sorted in place by k_sort
    ushort* hb   = (ushort*)(recs + EE);   // NN*128 bf16 (reused as h2: NN*64)
    ushort* a1   = hb + (size_t)NN * 128;  // NN*128 bf16

    // --- graph preprocessing (shared by both layers) ---
    hipMemsetAsync(gcount, 0, 512 * sizeof(int), stream);
    k_count<<<NCHK, 256, 0, stream>>>(dst, gcount);
    k_bscan<<<1, 512, 0, stream>>>(gcount, bofs, gcursor, rowptr);
    k_bin<<<NCHK, 256, 0, stream>>>(src, dst, ew, gcursor, recs);
    k_sort<<<NBKT, 256, 0, stream>>>(recs, bofs, dis, rowptr, epk);
    k_wmul<<<(EE + 255) / 256, 256, 0, stream>>>(epk, dis);

    // --- layer 1 ---
    k_gemm1<<<NN / 32, 256, 0, stream>>>(x, W1, hb);
    k_agg1<<<(NN * 64 + 255) / 256, 256, 0, stream>>>(rowptr, epk, dis, hb, b1, a1);

    // --- layer 2 (h2 reuses hb buffer) ---
    k_gemm2<<<(NN + 63) / 64, 256, 0, stream>>>(a1, W2, hb);
    k_agg2<<<(NN * 64 + 255) / 256, 256, 0, stream>>>(rowptr, epk, dis, hb, b2, out);
}